// Round 20
// baseline (193.119 us; speedup 1.0000x reference)
//
#include <hip/hip_runtime.h>
#include <hip/hip_bf16.h>

// ---------------------------------------------------------------------------
// WindGuidedCrossAttentionLayer: LN -> QKV proj -> biased attention -> out proj
// -> residual -> LN -> MLP(gelu) -> residual.  B=4, N=1024, D=768, H=12, hd=64.
// bf16 MFMA everywhere; fp32 residual path.
// ---------------------------------------------------------------------------

#define DIM 768
#define HID 3072
#define NHEAD 12
#define BATCH 4
#define SEQ 1024
#define ROWS (BATCH * SEQ)   // 4096
#define HD 64

typedef __attribute__((ext_vector_type(8))) __bf16 bf16x8;
typedef __attribute__((ext_vector_type(4))) float f32x4;
typedef __attribute__((ext_vector_type(4))) unsigned int u32x4;
typedef __attribute__((ext_vector_type(4))) unsigned short u16x4;

#define MFMA16(a, b, c) __builtin_amdgcn_mfma_f32_16x16x32_bf16((a), (b), (c), 0, 0, 0)

#define GLDS16(g, l)                                                         \
  __builtin_amdgcn_global_load_lds(                                          \
      (const __attribute__((address_space(1))) void*)(g),                    \
      (__attribute__((address_space(3))) void*)(l), 16, 0, 0)

__device__ __forceinline__ unsigned pk2(float lo, float hi) {
  unsigned a = __bfloat16_as_ushort(__float2bfloat16(lo));
  unsigned b = __bfloat16_as_ushort(__float2bfloat16(hi));
  return a | (b << 16);
}

// ---------------------------------------------------------------------------
// PREP (one launch): blocks [0,6912) = weight transposes (4x DxD + W1 + W2);
// blocks [6912, 6912+8192) = dual LayerNorm (query rows then context rows).
// ---------------------------------------------------------------------------
__global__ __launch_bounds__(256) void wg_prep(
    const float* __restrict__ Wq, const float* __restrict__ Wk,
    const float* __restrict__ Wv, const float* __restrict__ Wo,
    const float* __restrict__ W1, const float* __restrict__ W2,
    __hip_bfloat16* __restrict__ WqT, __hip_bfloat16* __restrict__ WkT,
    __hip_bfloat16* __restrict__ WvT, __hip_bfloat16* __restrict__ WoT,
    __hip_bfloat16* __restrict__ W1T, __hip_bfloat16* __restrict__ W2T,
    const float* __restrict__ query, const float* __restrict__ ln_q_w,
    const float* __restrict__ ln_q_b, const float* __restrict__ context,
    const float* __restrict__ ln_kv_w, const float* __restrict__ ln_kv_b,
    __hip_bfloat16* __restrict__ lnout) {
  const int id = blockIdx.x;
  const int t = threadIdx.x;
  if (id >= 6912) {
    // ---- dual LayerNorm ----
    const int row = id - 6912;
    const float* in = query;
    const float* w = ln_q_w;
    const float* b = ln_q_b;
    int lrow = row;
    if (row >= ROWS) {
      in = context; w = ln_kv_w; b = ln_kv_b; lrow = row - ROWS;
    }
    const float* p = in + (size_t)lrow * DIM;
    float v0 = p[t], v1 = p[t + 256], v2 = p[t + 512];
    float s = v0 + v1 + v2;
    float q = v0 * v0 + v1 * v1 + v2 * v2;
#pragma unroll
    for (int d = 1; d < 64; d <<= 1) {
      s += __shfl_xor(s, d);
      q += __shfl_xor(q, d);
    }
    __shared__ float ss[4], sq[4];
    if ((t & 63) == 0) {
      ss[t >> 6] = s;
      sq[t >> 6] = q;
    }
    __syncthreads();
    s = ss[0] + ss[1] + ss[2] + ss[3];
    q = sq[0] + sq[1] + sq[2] + sq[3];
    float mu = s * (1.0f / DIM);
    float var = q * (1.0f / DIM) - mu * mu;
    float rs = rsqrtf(var + 1e-5f);
    __hip_bfloat16* o = lnout + (size_t)row * DIM;
    o[t] = __float2bfloat16((v0 - mu) * rs * w[t] + b[t]);
    o[t + 256] = __float2bfloat16((v1 - mu) * rs * w[t + 256] + b[t + 256]);
    o[t + 512] = __float2bfloat16((v2 - mu) * rs * w[t + 512] + b[t + 512]);
    return;
  }
  // ---- weight transpose ----
  __shared__ float tile[32][33];
  const float* W;
  __hip_bfloat16* WT;
  int K, N, n0, k0;
  if (id < 2304) {
    const int z = id / 576, rem = id % 576;
    W = (z == 0) ? Wq : (z == 1) ? Wk : (z == 2) ? Wv : Wo;
    WT = (z == 0) ? WqT : (z == 1) ? WkT : (z == 2) ? WvT : WoT;
    K = DIM; N = DIM;
    n0 = (rem % 24) * 32; k0 = (rem / 24) * 32;
  } else if (id < 4608) {
    const int rem = id - 2304;
    W = W1; WT = W1T; K = DIM; N = HID;
    n0 = (rem % 96) * 32; k0 = (rem / 96) * 32;
  } else {
    const int rem = id - 4608;
    W = W2; WT = W2T; K = HID; N = DIM;
    n0 = (rem % 24) * 32; k0 = (rem / 24) * 32;
  }
  const int tx = t & 31, ty = t >> 5;  // ty 0..7
#pragma unroll
  for (int i = 0; i < 4; i++)
    tile[ty + i * 8][tx] = W[(size_t)(k0 + ty + i * 8) * N + n0 + tx];
  __syncthreads();
#pragma unroll
  for (int i = 0; i < 4; i++)
    WT[(size_t)(n0 + ty + i * 8) * K + k0 + tx] = __float2bfloat16(tile[tx][ty + i * 8]);
}

// ---------------------------------------------------------------------------
// LayerNorm over 768, fp32 in -> bf16 out (single-input; used for final LN)
// ---------------------------------------------------------------------------
__global__ __launch_bounds__(256) void wg_ln1(const float* __restrict__ in,
                                              const float* __restrict__ w,
                                              const float* __restrict__ b,
                                              __hip_bfloat16* __restrict__ outbuf) {
  int row = blockIdx.x;
  int t = threadIdx.x;
  const float* p = in + (size_t)row * DIM;
  float v0 = p[t], v1 = p[t + 256], v2 = p[t + 512];
  float s = v0 + v1 + v2;
  float q = v0 * v0 + v1 * v1 + v2 * v2;
#pragma unroll
  for (int d = 1; d < 64; d <<= 1) {
    s += __shfl_xor(s, d);
    q += __shfl_xor(q, d);
  }
  __shared__ float ss[4], sq[4];
  if ((t & 63) == 0) {
    ss[t >> 6] = s;
    sq[t >> 6] = q;
  }
  __syncthreads();
  s = ss[0] + ss[1] + ss[2] + ss[3];
  q = sq[0] + sq[1] + sq[2] + sq[3];
  float mu = s * (1.0f / DIM);
  float var = q * (1.0f / DIM) - mu * mu;
  float rs = rsqrtf(var + 1e-5f);
  __hip_bfloat16* o = outbuf + (size_t)row * DIM;
  o[t] = __float2bfloat16((v0 - mu) * rs * w[t] + b[t]);
  o[t + 256] = __float2bfloat16((v1 - mu) * rs * w[t + 256] + b[t + 256]);
  o[t + 512] = __float2bfloat16((v2 - mu) * rs * w[t + 512] + b[t + 512]);
}

// ---------------------------------------------------------------------------
// GEMM v3 (m97-structure A/B): 128x128 tile, BK=32, 512 threads = 8 waves,
// SINGLE-buffer LDS (16KB) + 2 barriers per K-step -> wave-capped 4 blocks/CU
// (32 waves/CU, +33% TLP vs 3-buffer 48KB).  Cross-block implicit overlap
// hides the per-block barrier drain (m114).  T1 XCD-chunked swizzle kept.
// MODE 3: resid-add f32 (o-proj); 4: gelu bf16;
// 6: fused QKV (bias from bias/resid/aux = bq/bk/bv); 7: split-K bf16 partial.
// ---------------------------------------------------------------------------
template <int MODE>
__global__ __launch_bounds__(512) void wg_gemm(const __hip_bfloat16* __restrict__ A,
                                               const __hip_bfloat16* __restrict__ BT,
                                               const float* __restrict__ bias,
                                               void* __restrict__ Cout,
                                               const float* __restrict__ resid,
                                               float* __restrict__ aux,
                                               int N, int Kloop, int Kstride, float p0,
                                               int cpx) {
  __shared__ __hip_bfloat16 As[128 * 32];
  __shared__ __hip_bfloat16 Bs[128 * 32];
  const int t = threadIdx.x;
  const int lane = t & 63;
  const int wave = t >> 6;           // 0..7
  const int wr = wave >> 1, wc = wave & 1;
  const int lhi = lane >> 4, llo = lane & 15;
  const int nbn = N >> 7;
  // T1 XCD-chunked swizzle (bijective: gridDim.x % 8 == 0)
  const int bid = blockIdx.x;
  const int wid = (bid & 7) * cpx + (bid >> 3);
  const int bm = wid / nbn, bn = wid % nbn;
  const int koff = (MODE == 7) ? blockIdx.y * Kloop : 0;

  const __hip_bfloat16* Ause = A;
  if (MODE == 6 && bn >= 6) Ause = A + (size_t)ROWS * DIM;  // kvln

  const int srow = t >> 2;
  const int sg = ((t & 3) ^ ((srow >> 1) & 3)) * 8;
  const __hip_bfloat16* Ag = Ause + (size_t)(bm * 128 + srow) * Kstride + koff + sg;
  const __hip_bfloat16* Bg = BT + (size_t)(bn * 128 + srow) * Kstride + koff + sg;

  f32x4 zero = {0.f, 0.f, 0.f, 0.f};
  f32x4 acc[2][4];
#pragma unroll
  for (int i = 0; i < 2; i++)
#pragma unroll
    for (int j = 0; j < 4; j++) acc[i][j] = zero;

  const int nk = Kloop >> 5;   // K-steps of 32

  for (int kt = 0; kt < nk; kt++) {
    __syncthreads();   // all waves done reading the buffer (previous step)
    GLDS16(Ag + kt * 32, &As[t * 8]);
    GLDS16(Bg + kt * 32, &Bs[t * 8]);
    __syncthreads();   // compiler drains vmcnt before barrier -> tile ready
    bf16x8 af[2], bfr[4];
#pragma unroll
    for (int i = 0; i < 2; i++) {
      const int row = wr * 32 + i * 16 + llo;
      af[i] = *reinterpret_cast<const bf16x8*>(
          &As[row * 32 + ((lhi ^ ((row >> 1) & 3)) << 3)]);
    }
#pragma unroll
    for (int j = 0; j < 4; j++) {
      const int row = wc * 64 + j * 16 + llo;
      bfr[j] = *reinterpret_cast<const bf16x8*>(
          &Bs[row * 32 + ((lhi ^ ((row >> 1) & 3)) << 3)]);
    }
    __builtin_amdgcn_s_setprio(1);
#pragma unroll
    for (int i = 0; i < 2; i++)
#pragma unroll
      for (int j = 0; j < 4; j++) acc[i][j] = MFMA16(af[i], bfr[j], acc[i][j]);
    __builtin_amdgcn_s_setprio(0);
  }

#pragma unroll
  for (int i = 0; i < 2; i++) {
    int gr = bm * 128 + wr * 32 + i * 16 + lhi * 4;
#pragma unroll
    for (int j = 0; j < 4; j++) {
      int gc = bn * 128 + wc * 64 + j * 16 + llo;
      int sec = 0, n2 = gc;
      float bval;
      if (MODE == 6) {
        sec = gc / 768;
        n2 = gc - sec * 768;
        const float* bp = (sec == 0) ? bias : (sec == 1) ? resid : (const float*)aux;
        bval = bp[n2];
      } else if (MODE == 7) {
        bval = 0.f;
      } else {
        bval = bias[gc];
      }
#pragma unroll
      for (int r = 0; r < 4; r++) {
        float v = acc[i][j][r] + bval;
        int row = gr + r;
        size_t idx = (size_t)row * N + gc;
        if (MODE == 3) {
          aux[idx] = resid[idx] + v;
        } else if (MODE == 4) {
          float x3 = v * v * v;
          float z = -2.302208f * v - 0.102943f * x3;
          float g = v / (1.0f + exp2f(z));
          ((__hip_bfloat16*)Cout)[idx] = __float2bfloat16(g);
        } else if (MODE == 7) {
          ((__hip_bfloat16*)aux)[(size_t)blockIdx.y * ROWS * N + idx] =
              __float2bfloat16(v);
        } else if (MODE == 6) {
          __hip_bfloat16* base = (__hip_bfloat16*)Cout;
          if (sec == 0) {
            base[(size_t)row * DIM + n2] = __float2bfloat16(v * p0);
          } else if (sec == 1) {
            base[(size_t)ROWS * DIM + (size_t)row * DIM + n2] = __float2bfloat16(v);
          } else {
            int b_ = row >> 10, n_ = row & 1023;
            int h_ = n2 >> 6, d_ = n2 & 63;
            base[(size_t)2 * ROWS * DIM +
                 (((size_t)(b_ * NHEAD + h_) * HD + d_) << 10) + n_] = __float2bfloat16(v);
          }
        }
      }
    }
  }
}

// ---------------------------------------------------------------------------
// Split-K reduce (bf16 partials): out = resid + bias + sum_{c<4} partial[c]
// ---------------------------------------------------------------------------
__global__ __launch_bounds__(256) void wg_redb(const __hip_bfloat16* __restrict__ partial,
                                               const float* __restrict__ resid,
                                               const float* __restrict__ bias,
                                               float* __restrict__ out) {
  const int i = blockIdx.x * 256 + threadIdx.x;   // f32x4 index
  const int NF4 = ROWS * DIM / 4;
  if (i >= NF4) return;
  f32x4 p = {0.f, 0.f, 0.f, 0.f};
#pragma unroll
  for (int c = 0; c < 4; c++) {
    u16x4 h = *reinterpret_cast<const u16x4*>(&partial[(size_t)c * ROWS * DIM + i * 4]);
#pragma unroll
    for (int r = 0; r < 4; r++) p[r] += __uint_as_float((unsigned)h[r] << 16);
  }
  f32x4 rr = ((const f32x4*)resid)[i];
  f32x4 bv = ((const f32x4*)bias)[i % (DIM / 4)];
  ((f32x4*)out)[i] = rr + p + bv;
}

// ---------------------------------------------------------------------------
// Flash attention v11 (proven 53.5us round 18): no-max softmax + deferred
// l-reduction; swapped QK^T, register P-transpose, wind prefetch, XCD grid.
// ---------------------------------------------------------------------------
__global__ __launch_bounds__(256) void wg_attn11(const __hip_bfloat16* __restrict__ Q,
                                                 const __hip_bfloat16* __restrict__ Kb,
                                                 const __hip_bfloat16* __restrict__ Vt,
                                                 const float* __restrict__ wb,
                                                 const float* __restrict__ beta,
                                                 __hip_bfloat16* __restrict__ O) {
  __shared__ __hip_bfloat16 Ks[2][4096];
  __shared__ __hip_bfloat16 Vs[2][4096];
  const int t = threadIdx.x;
  const int lane = t & 63;
  const int lhi = lane >> 4, llo = lane & 15;

  const int bid = blockIdx.x;
  const int wid = (bid & 7) * 96 + (bid >> 3);
  const int h = wid % NHEAD;
  const int g = wid / NHEAD;       // 0..63
  const int qt = g & 15;
  const int b = g >> 4;
  const float betah = beta[h] * 1.44269504089f;   // exp2 domain

  const int w = t >> 6;
  const size_t qrow0 = (size_t)b * SEQ + qt * 64 + w * 16;
  const __hip_bfloat16* Qp = Q + qrow0 * DIM + h * HD;
  bf16x8 a0 = *reinterpret_cast<const bf16x8*>(&Qp[(size_t)llo * DIM + lhi * 8]);
  bf16x8 a1 = *reinterpret_cast<const bf16x8*>(&Qp[(size_t)llo * DIM + 32 + lhi * 8]);

  const __hip_bfloat16* Kg = Kb + (size_t)b * SEQ * DIM + h * HD;
  const __hip_bfloat16* Vg = Vt + (size_t)(b * NHEAD + h) * HD * SEQ;
  const float* wrow = wb + (qrow0 + llo) * SEQ;

  const int slot0 = t, slot1 = t + 256;
  const int r0 = slot0 >> 3, c0 = (slot0 & 7) ^ (r0 & 7);
  const int r1 = slot1 >> 3, c1 = (slot1 & 7) ^ (r1 & 7);

  auto stage = [&](int buf, int kb) {
    GLDS16(Kg + (size_t)(kb + r0) * DIM + c0 * 8, &Ks[buf][slot0 * 8]);
    GLDS16(Kg + (size_t)(kb + r1) * DIM + c1 * 8, &Ks[buf][slot1 * 8]);
    GLDS16(Vg + (size_t)r0 * SEQ + kb + c0 * 8, &Vs[buf][slot0 * 8]);
    GLDS16(Vg + (size_t)r1 * SEQ + kb + c1 * 8, &Vs[buf][slot1 * 8]);
  };

  f32x4 zero = {0.f, 0.f, 0.f, 0.f};
  f32x4 oc[4];
#pragma unroll
  for (int c = 0; c < 4; c++) oc[c] = zero;
  float lacc = 0.f;

  f32x4 wv[4];
#pragma unroll
  for (int c2 = 0; c2 < 4; c2++)
    wv[c2] = *reinterpret_cast<const f32x4*>(&wrow[c2 * 16 + lhi * 4]);

  stage(0, 0);
  __syncthreads();
  int cur = 0;

  const int srcA = (lane & 15) | ((lane & 16) << 1);  // llo + 32*(lhi&1)
  const bool chi = (lane & 32) != 0;                  // lhi>>1

  for (int kt = 0; kt < SEQ / 64; kt++) {
    const int kb = kt * 64;
    f32x4 wvn[4];
    if (kt < SEQ / 64 - 1) {
      stage(cur ^ 1, kb + 64);
#pragma unroll
      for (int c2 = 0; c2 < 4; c2++)
        wvn[c2] = *reinterpret_cast<const f32x4*>(&wrow[kb + 64 + c2 * 16 + lhi * 4]);
    }

    // ---- swapped QK^T: lane holds S^T[kv=c2*16+lhi*4+r][q=llo] ----
    f32x4 sv[4];
    __builtin_amdgcn_s_setprio(1);
#pragma unroll
    for (int c2 = 0; c2 < 4; c2++) {
      const int row = c2 * 16 + llo;
      bf16x8 k0 = *reinterpret_cast<const bf16x8*>(
          &Ks[cur][((row << 3) + (lhi ^ (row & 7))) << 3]);
      bf16x8 k1 = *reinterpret_cast<const bf16x8*>(
          &Ks[cur][((row << 3) + ((4 + lhi) ^ (row & 7))) << 3]);
      f32x4 s_ = zero;
      s_ = MFMA16(k0, a0, s_);
      s_ = MFMA16(k1, a1, s_);
      sv[c2] = s_;
    }
    __builtin_amdgcn_s_setprio(0);

    // ---- bias + exp2 (no max; scale cancels in O/l) ----
#pragma unroll
    for (int c2 = 0; c2 < 4; c2++)
#pragma unroll
      for (int r = 0; r < 4; r++)
        sv[c2][r] = exp2f(sv[c2][r] + betah * wv[c2][r]);

    // ---- per-lane partial sum (cross-lane deferred to epilogue) ----
    f32x4 s4;
#pragma unroll
    for (int r = 0; r < 4; r++) s4[r] = (sv[0][r] + sv[1][r]) + (sv[2][r] + sv[3][r]);
    lacc += (s4[0] + s4[1]) + (s4[2] + s4[3]);

    // ---- P transpose in registers ----
    unsigned p01[4], p23[4];
#pragma unroll
    for (int c2 = 0; c2 < 4; c2++) {
      p01[c2] = pk2(sv[c2][0], sv[c2][1]);
      p23[c2] = pk2(sv[c2][2], sv[c2][3]);
    }
    unsigned a01_0A = (unsigned)__shfl((int)p01[0], srcA);
    unsigned a01_1A = (unsigned)__shfl((int)p01[1], srcA);
    unsigned a23_0A = (unsigned)__shfl((int)p23[0], srcA);
    unsigned a23_1A = (unsigned)__shfl((int)p23[1], srcA);
    unsigned a01_0B = (unsigned)__shfl((int)p01[0], srcA + 16);
    unsigned a01_1B = (unsigned)__shfl((int)p01[1], srcA + 16);
    unsigned a23_0B = (unsigned)__shfl((int)p23[0], srcA + 16);
    unsigned a23_1B = (unsigned)__shfl((int)p23[1], srcA + 16);
    unsigned b01_2A = (unsigned)__shfl((int)p01[2], srcA);
    unsigned b01_3A = (unsigned)__shfl((int)p01[3], srcA);
    unsigned b23_2A = (unsigned)__shfl((int)p23[2], srcA);
    unsigned b23_3A = (unsigned)__shfl((int)p23[3], srcA);
    unsigned b01_2B = (unsigned)__shfl((int)p01[2], srcA + 16);
    unsigned b01_3B = (unsigned)__shfl((int)p01[3], srcA + 16);
    unsigned b23_2B = (unsigned)__shfl((int)p23[2], srcA + 16);
    unsigned b23_3B = (unsigned)__shfl((int)p23[3], srcA + 16);
    u32x4 t0, t1;
    t0[0] = chi ? a01_1A : a01_0A;
    t0[1] = chi ? a23_1A : a23_0A;
    t0[2] = chi ? a01_1B : a01_0B;
    t0[3] = chi ? a23_1B : a23_0B;
    t1[0] = chi ? b01_3A : b01_2A;
    t1[1] = chi ? b23_3A : b23_2A;
    t1[2] = chi ? b01_3B : b01_2B;
    t1[3] = chi ? b23_3B : b23_2B;
    bf16x8 pf0 = __builtin_bit_cast(bf16x8, t0);
    bf16x8 pf1 = __builtin_bit_cast(bf16x8, t1);

    // ---- PV ----
    __builtin_amdgcn_s_setprio(1);
#pragma unroll
    for (int c = 0; c < 4; c++) {
      const int row = c * 16 + llo;
      bf16x8 v0 = *reinterpret_cast<const bf16x8*>(
          &Vs[cur][((row << 3) + (lhi ^ (row & 7))) << 3]);
      bf16x8 v1 = *reinterpret_cast<const bf16x8*>(
          &Vs[cur][((row << 3) + ((4 + lhi) ^ (row & 7))) << 3]);
      oc[c] = MFMA16(pf0, v0, oc[c]);
      oc[c] = MFMA16(pf1, v1, oc[c]);
    }
    __builtin_amdgcn_s_setprio(0);

    if (kt < SEQ / 64 - 1) {
#pragma unroll
      for (int c2 = 0; c2 < 4; c2++) wv[c2] = wvn[c2];
    }
    __syncthreads();
    cur ^= 1;
  }

  // epilogue: complete the l reduction (2 shuffles, once), then normalize
  float l_ = lacc;
  l_ += __shfl_xor(l_, 16);
  l_ += __shfl_xor(l_, 32);
  float iv[4];
  float invl = 1.0f / l_;
#pragma unroll
  for (int r = 0; r < 4; r++) iv[r] = __shfl(invl, lhi * 4 + r);
  __hip_bfloat16* Op = O + qrow0 * DIM + h * HD;
#pragma unroll
  for (int c = 0; c < 4; c++)
#pragma unroll
    for (int r = 0; r < 4; r++)
      Op[(size_t)(lhi * 4 + r) * DIM + c * 16 + llo] = __float2bfloat16(oc[c][r] * iv[r]);
}

// ---------------------------------------------------------------------------
// Launch
// ---------------------------------------------------------------------------
extern "C" void kernel_launch(void* const* d_in, const int* in_sizes, int n_in,
                              void* d_out, int out_size, void* d_ws, size_t ws_size,
                              hipStream_t stream) {
  const float* query = (const float*)d_in[0];
  const float* context = (const float*)d_in[1];
  const float* wind = (const float*)d_in[2];
  const float* ln_q_w = (const float*)d_in[3];
  const float* ln_q_b = (const float*)d_in[4];
  const float* ln_kv_w = (const float*)d_in[5];
  const float* ln_kv_b = (const float*)d_in[6];
  const float* Wq = (const float*)d_in[7];
  const float* bq = (const float*)d_in[8];
  const float* Wk = (const float*)d_in[9];
  const float* bk = (const float*)d_in[10];
  const float* Wv = (const float*)d_in[11];
  const float* bv = (const float*)d_in[12];
  const float* Wo = (const float*)d_in[13];
  const float* bo = (const float*)d_in[14];
  const float* beta = (const float*)d_in[15];
  const float* ln_f_w = (const float*)d_in[16];
  const float* ln_f_b = (const float*)d_in[17];
  const float* W1 = (const float*)d_in[18];
  const float* b1 = (const float*)d_in[19];
  const float* W2 = (const float*)d_in[20];
  const float* b2 = (const float*)d_in[21];
  float* out = (float*)d_out;

  char* ws = (char*)d_ws;
  size_t off = 0;
  auto take = [&](size_t bytes) -> char* {
    char* p = ws + off;
    off += (bytes + 255) & ~(size_t)255;
    return p;
  };
  const size_t actB = (size_t)ROWS * DIM * 2;
  __hip_bfloat16* qln = (__hip_bfloat16*)take(actB);
  __hip_bfloat16* kvln = (__hip_bfloat16*)take(actB);
  __hip_bfloat16* qb = (__hip_bfloat16*)take(actB);
  __hip_bfloat16* kbuf = (__hip_bfloat16*)take(actB);
  __hip_bfloat16* vt = (__hip_bfloat16*)take(actB);
  __hip_bfloat16* aout = (__hip_bfloat16*)take(actB);
  __hip_bfloat16* hbuf = (__hip_bfloat16*)take(actB);
  float* xbuf = (float*)take((size_t)ROWS * DIM * 4);
  __hip_bfloat16* hid = (__hip_bfloat16*)take((size_t)ROWS * HID * 2);
  __hip_bfloat16* WqT = (__hip_bfloat16*)take((size_t)DIM * DIM * 2);
  __hip_bfloat16* WkT = (__hip_bfloat16*)take((size_t)DIM * DIM * 2);
  __hip_bfloat16* WvT = (__hip_bfloat16*)take((size_t)DIM * DIM * 2);
  __hip_bfloat16* WoT = (__hip_bfloat16*)take((size_t)DIM * DIM * 2);
  __hip_bfloat16* W1T = (__hip_bfloat16*)take((size_t)DIM * HID * 2);
  __hip_bfloat16* W2T = (__hip_bfloat16*)take((size_t)HID * DIM * 2);
  __hip_bfloat16* kpart = (__hip_bfloat16*)take((size_t)4 * ROWS * DIM * 2);  // bf16 partials

  // prep: all weight transposes + dual LN in one launch
  wg_prep<<<6912 + 2 * ROWS, 256, 0, stream>>>(
      Wq, Wk, Wv, Wo, W1, W2, WqT, WkT, WvT, WoT, W1T, W2T,
      query, ln_q_w, ln_q_b, context, ln_kv_w, ln_kv_b, qln);

  const float scale = 0.125f * 1.44269504089f;  // hd^-0.5 * log2(e)
  // fused QKV: bias pointers bq/bk/bv passed via bias/resid/aux
  wg_gemm<6><<<32 * 18, 512, 0, stream>>>(qln, WqT, bq, qb, bk, (float*)bv,
                                          2304, DIM, DIM, scale, 32 * 18 / 8);

  wg_attn11<<<768, 256, 0, stream>>>(qb, kbuf, vt, wind, beta, aout);

  const int g768 = (ROWS / 128) * (DIM / 128);   // 192
  const int g3072 = (ROWS / 128) * (HID / 128);  // 768
  // O-proj fused: xbuf = query + aout*Wo + bo
  wg_gemm<3><<<g768, 512, 0, stream>>>(aout, WoT, bo, nullptr, query, xbuf,
                                       DIM, DIM, DIM, 0.f, g768 / 8);
  wg_ln1<<<ROWS, 256, 0, stream>>>(xbuf, ln_f_w, ln_f_b, hbuf);
  wg_gemm<4><<<g3072, 512, 0, stream>>>(hbuf, W1T, b1, hid, nullptr, nullptr,
                                        HID, DIM, DIM, 0.f, g3072 / 8);
  // MLP2 split-K=4, bf16 partials
  wg_gemm<7><<<dim3(g768, 4), 512, 0, stream>>>(hid, W2T, nullptr, nullptr, nullptr,
                                                (float*)kpart, DIM, HID / 4, HID, 0.f,
                                                g768 / 8);
  wg_redb<<<(ROWS * DIM / 4 + 255) / 256, 256, 0, stream>>>(kpart, xbuf, b2, out);
}

// Round 21
// 187.280 us; speedup vs baseline: 1.0312x; 1.0312x over previous
//
#include <hip/hip_runtime.h>
#include <hip/hip_bf16.h>

// ---------------------------------------------------------------------------
// WindGuidedCrossAttentionLayer: LN -> QKV proj -> biased attention -> out proj
// -> residual -> LN -> MLP(gelu) -> residual.  B=4, N=1024, D=768, H=12, hd=64.
// bf16 MFMA everywhere; fp32 residual path.  BEST CONFIG (round 19, 187.5us):
//  - wg_prep: merged weight transposes + dual LN
//  - wg_gemm: 128x128/BK=32, 8 waves, 3-buffer counted-vmcnt pipeline, T1 XCD
//    swizzle, fused epilogues (QKV sections / resid-add / gelu / bf16 splitK)
//  - wg_attn11: swapped QK^T, no-max exp2 softmax, deferred l-reduce,
//    register P-transpose, wind prefetch, XCD-chunked grid
//  - MLP2 split-K=4 with bf16 partials + fused reduce
// ---------------------------------------------------------------------------

#define DIM 768
#define HID 3072
#define NHEAD 12
#define BATCH 4
#define SEQ 1024
#define ROWS (BATCH * SEQ)   // 4096
#define HD 64

typedef __attribute__((ext_vector_type(8))) __bf16 bf16x8;
typedef __attribute__((ext_vector_type(4))) float f32x4;
typedef __attribute__((ext_vector_type(4))) unsigned int u32x4;
typedef __attribute__((ext_vector_type(4))) unsigned short u16x4;

#define MFMA16(a, b, c) __builtin_amdgcn_mfma_f32_16x16x32_bf16((a), (b), (c), 0, 0, 0)

#define GLDS16(g, l)                                                         \
  __builtin_amdgcn_global_load_lds(                                          \
      (const __attribute__((address_space(1))) void*)(g),                    \
      (__attribute__((address_space(3))) void*)(l), 16, 0, 0)

__device__ __forceinline__ unsigned pk2(float lo, float hi) {
  unsigned a = __bfloat16_as_ushort(__float2bfloat16(lo));
  unsigned b = __bfloat16_as_ushort(__float2bfloat16(hi));
  return a | (b << 16);
}

// ---------------------------------------------------------------------------
// PREP (one launch): blocks [0,6912) = weight transposes (4x DxD + W1 + W2);
// blocks [6912, 6912+8192) = dual LayerNorm (query rows then context rows).
// ---------------------------------------------------------------------------
__global__ __launch_bounds__(256) void wg_prep(
    const float* __restrict__ Wq, const float* __restrict__ Wk,
    const float* __restrict__ Wv, const float* __restrict__ Wo,
    const float* __restrict__ W1, const float* __restrict__ W2,
    __hip_bfloat16* __restrict__ WqT, __hip_bfloat16* __restrict__ WkT,
    __hip_bfloat16* __restrict__ WvT, __hip_bfloat16* __restrict__ WoT,
    __hip_bfloat16* __restrict__ W1T, __hip_bfloat16* __restrict__ W2T,
    const float* __restrict__ query, const float* __restrict__ ln_q_w,
    const float* __restrict__ ln_q_b, const float* __restrict__ context,
    const float* __restrict__ ln_kv_w, const float* __restrict__ ln_kv_b,
    __hip_bfloat16* __restrict__ lnout) {
  const int id = blockIdx.x;
  const int t = threadIdx.x;
  if (id >= 6912) {
    // ---- dual LayerNorm ----
    const int row = id - 6912;
    const float* in = query;
    const float* w = ln_q_w;
    const float* b = ln_q_b;
    int lrow = row;
    if (row >= ROWS) {
      in = context; w = ln_kv_w; b = ln_kv_b; lrow = row - ROWS;
    }
    const float* p = in + (size_t)lrow * DIM;
    float v0 = p[t], v1 = p[t + 256], v2 = p[t + 512];
    float s = v0 + v1 + v2;
    float q = v0 * v0 + v1 * v1 + v2 * v2;
#pragma unroll
    for (int d = 1; d < 64; d <<= 1) {
      s += __shfl_xor(s, d);
      q += __shfl_xor(q, d);
    }
    __shared__ float ss[4], sq[4];
    if ((t & 63) == 0) {
      ss[t >> 6] = s;
      sq[t >> 6] = q;
    }
    __syncthreads();
    s = ss[0] + ss[1] + ss[2] + ss[3];
    q = sq[0] + sq[1] + sq[2] + sq[3];
    float mu = s * (1.0f / DIM);
    float var = q * (1.0f / DIM) - mu * mu;
    float rs = rsqrtf(var + 1e-5f);
    __hip_bfloat16* o = lnout + (size_t)row * DIM;
    o[t] = __float2bfloat16((v0 - mu) * rs * w[t] + b[t]);
    o[t + 256] = __float2bfloat16((v1 - mu) * rs * w[t + 256] + b[t + 256]);
    o[t + 512] = __float2bfloat16((v2 - mu) * rs * w[t + 512] + b[t + 512]);
    return;
  }
  // ---- weight transpose ----
  __shared__ float tile[32][33];
  const float* W;
  __hip_bfloat16* WT;
  int K, N, n0, k0;
  if (id < 2304) {
    const int z = id / 576, rem = id % 576;
    W = (z == 0) ? Wq : (z == 1) ? Wk : (z == 2) ? Wv : Wo;
    WT = (z == 0) ? WqT : (z == 1) ? WkT : (z == 2) ? WvT : WoT;
    K = DIM; N = DIM;
    n0 = (rem % 24) * 32; k0 = (rem / 24) * 32;
  } else if (id < 4608) {
    const int rem = id - 2304;
    W = W1; WT = W1T; K = DIM; N = HID;
    n0 = (rem % 96) * 32; k0 = (rem / 96) * 32;
  } else {
    const int rem = id - 4608;
    W = W2; WT = W2T; K = HID; N = DIM;
    n0 = (rem % 24) * 32; k0 = (rem / 24) * 32;
  }
  const int tx = t & 31, ty = t >> 5;  // ty 0..7
#pragma unroll
  for (int i = 0; i < 4; i++)
    tile[ty + i * 8][tx] = W[(size_t)(k0 + ty + i * 8) * N + n0 + tx];
  __syncthreads();
#pragma unroll
  for (int i = 0; i < 4; i++)
    WT[(size_t)(n0 + ty + i * 8) * K + k0 + tx] = __float2bfloat16(tile[tx][ty + i * 8]);
}

// ---------------------------------------------------------------------------
// LayerNorm over 768, fp32 in -> bf16 out (single-input; used for final LN)
// ---------------------------------------------------------------------------
__global__ __launch_bounds__(256) void wg_ln1(const float* __restrict__ in,
                                              const float* __restrict__ w,
                                              const float* __restrict__ b,
                                              __hip_bfloat16* __restrict__ outbuf) {
  int row = blockIdx.x;
  int t = threadIdx.x;
  const float* p = in + (size_t)row * DIM;
  float v0 = p[t], v1 = p[t + 256], v2 = p[t + 512];
  float s = v0 + v1 + v2;
  float q = v0 * v0 + v1 * v1 + v2 * v2;
#pragma unroll
  for (int d = 1; d < 64; d <<= 1) {
    s += __shfl_xor(s, d);
    q += __shfl_xor(q, d);
  }
  __shared__ float ss[4], sq[4];
  if ((t & 63) == 0) {
    ss[t >> 6] = s;
    sq[t >> 6] = q;
  }
  __syncthreads();
  s = ss[0] + ss[1] + ss[2] + ss[3];
  q = sq[0] + sq[1] + sq[2] + sq[3];
  float mu = s * (1.0f / DIM);
  float var = q * (1.0f / DIM) - mu * mu;
  float rs = rsqrtf(var + 1e-5f);
  __hip_bfloat16* o = outbuf + (size_t)row * DIM;
  o[t] = __float2bfloat16((v0 - mu) * rs * w[t] + b[t]);
  o[t + 256] = __float2bfloat16((v1 - mu) * rs * w[t + 256] + b[t + 256]);
  o[t + 512] = __float2bfloat16((v2 - mu) * rs * w[t + 512] + b[t + 512]);
}

// ---------------------------------------------------------------------------
// GEMM (round-19 proven best): 128x128 tile, BK=32, 512 threads = 8 waves,
// wave tile 32x64 (acc 2x4), TRIPLE-buffered LDS + counted vmcnt pipeline,
// T1 XCD-chunked blockIdx swizzle (wid = (bid&7)*cpx + bid>>3).
// MODE 3: resid-add f32 (o-proj); 4: gelu bf16;
// 6: fused QKV (bias from bias/resid/aux = bq/bk/bv); 7: split-K bf16 partial.
// ---------------------------------------------------------------------------
template <int MODE>
__global__ __launch_bounds__(512) void wg_gemm(const __hip_bfloat16* __restrict__ A,
                                               const __hip_bfloat16* __restrict__ BT,
                                               const float* __restrict__ bias,
                                               void* __restrict__ Cout,
                                               const float* __restrict__ resid,
                                               float* __restrict__ aux,
                                               int N, int Kloop, int Kstride, float p0,
                                               int cpx) {
  __shared__ __hip_bfloat16 As[3][128 * 32];
  __shared__ __hip_bfloat16 Bs[3][128 * 32];
  const int t = threadIdx.x;
  const int lane = t & 63;
  const int wave = t >> 6;           // 0..7
  const int wr = wave >> 1, wc = wave & 1;
  const int lhi = lane >> 4, llo = lane & 15;
  const int nbn = N >> 7;
  // T1 XCD-chunked swizzle (bijective: gridDim.x % 8 == 0)
  const int bid = blockIdx.x;
  const int wid = (bid & 7) * cpx + (bid >> 3);
  const int bm = wid / nbn, bn = wid % nbn;
  const int koff = (MODE == 7) ? blockIdx.y * Kloop : 0;

  const __hip_bfloat16* Ause = A;
  if (MODE == 6 && bn >= 6) Ause = A + (size_t)ROWS * DIM;  // kvln

  const int srow = t >> 2;
  const int sg = ((t & 3) ^ ((srow >> 1) & 3)) * 8;
  const __hip_bfloat16* Ag = Ause + (size_t)(bm * 128 + srow) * Kstride + koff + sg;
  const __hip_bfloat16* Bg = BT + (size_t)(bn * 128 + srow) * Kstride + koff + sg;

  f32x4 zero = {0.f, 0.f, 0.f, 0.f};
  f32x4 acc[2][4];
#pragma unroll
  for (int i = 0; i < 2; i++)
#pragma unroll
    for (int j = 0; j < 4; j++) acc[i][j] = zero;

  const int nk = Kloop >> 5;   // K-steps of 32

  GLDS16(Ag, &As[0][t * 8]);
  GLDS16(Bg, &Bs[0][t * 8]);
  GLDS16(Ag + 32, &As[1][t * 8]);
  GLDS16(Bg + 32, &Bs[1][t * 8]);

  int buf = 0;
  for (int kt = 0; kt < nk; kt++) {
    if (kt < nk - 1) {
      asm volatile("s_waitcnt vmcnt(2)" ::: "memory");
    } else {
      asm volatile("s_waitcnt vmcnt(0)" ::: "memory");
    }
    __builtin_amdgcn_s_barrier();
    asm volatile("" ::: "memory");
    if (kt + 2 < nk) {
      int nbuf = buf + 2;
      if (nbuf >= 3) nbuf -= 3;
      GLDS16(Ag + (kt + 2) * 32, &As[nbuf][t * 8]);
      GLDS16(Bg + (kt + 2) * 32, &Bs[nbuf][t * 8]);
    }
    bf16x8 af[2], bfr[4];
#pragma unroll
    for (int i = 0; i < 2; i++) {
      const int row = wr * 32 + i * 16 + llo;
      af[i] = *reinterpret_cast<const bf16x8*>(
          &As[buf][row * 32 + ((lhi ^ ((row >> 1) & 3)) << 3)]);
    }
#pragma unroll
    for (int j = 0; j < 4; j++) {
      const int row = wc * 64 + j * 16 + llo;
      bfr[j] = *reinterpret_cast<const bf16x8*>(
          &Bs[buf][row * 32 + ((lhi ^ ((row >> 1) & 3)) << 3)]);
    }
    __builtin_amdgcn_s_setprio(1);
#pragma unroll
    for (int i = 0; i < 2; i++)
#pragma unroll
      for (int j = 0; j < 4; j++) acc[i][j] = MFMA16(af[i], bfr[j], acc[i][j]);
    __builtin_amdgcn_s_setprio(0);
    buf++;
    if (buf == 3) buf = 0;
  }

#pragma unroll
  for (int i = 0; i < 2; i++) {
    int gr = bm * 128 + wr * 32 + i * 16 + lhi * 4;
#pragma unroll
    for (int j = 0; j < 4; j++) {
      int gc = bn * 128 + wc * 64 + j * 16 + llo;
      int sec = 0, n2 = gc;
      float bval;
      if (MODE == 6) {
        sec = gc / 768;
        n2 = gc - sec * 768;
        const float* bp = (sec == 0) ? bias : (sec == 1) ? resid : (const float*)aux;
        bval = bp[n2];
      } else if (MODE == 7) {
        bval = 0.f;
      } else {
        bval = bias[gc];
      }
#pragma unroll
      for (int r = 0; r < 4; r++) {
        float v = acc[i][j][r] + bval;
        int row = gr + r;
        size_t idx = (size_t)row * N + gc;
        if (MODE == 3) {
          aux[idx] = resid[idx] + v;
        } else if (MODE == 4) {
          float x3 = v * v * v;
          float z = -2.302208f * v - 0.102943f * x3;
          float g = v / (1.0f + exp2f(z));
          ((__hip_bfloat16*)Cout)[idx] = __float2bfloat16(g);
        } else if (MODE == 7) {
          ((__hip_bfloat16*)aux)[(size_t)blockIdx.y * ROWS * N + idx] =
              __float2bfloat16(v);
        } else if (MODE == 6) {
          __hip_bfloat16* base = (__hip_bfloat16*)Cout;
          if (sec == 0) {
            base[(size_t)row * DIM + n2] = __float2bfloat16(v * p0);
          } else if (sec == 1) {
            base[(size_t)ROWS * DIM + (size_t)row * DIM + n2] = __float2bfloat16(v);
          } else {
            int b_ = row >> 10, n_ = row & 1023;
            int h_ = n2 >> 6, d_ = n2 & 63;
            base[(size_t)2 * ROWS * DIM +
                 (((size_t)(b_ * NHEAD + h_) * HD + d_) << 10) + n_] = __float2bfloat16(v);
          }
        }
      }
    }
  }
}

// ---------------------------------------------------------------------------
// Split-K reduce (bf16 partials): out = resid + bias + sum_{c<4} partial[c]
// ---------------------------------------------------------------------------
__global__ __launch_bounds__(256) void wg_redb(const __hip_bfloat16* __restrict__ partial,
                                               const float* __restrict__ resid,
                                               const float* __restrict__ bias,
                                               float* __restrict__ out) {
  const int i = blockIdx.x * 256 + threadIdx.x;   // f32x4 index
  const int NF4 = ROWS * DIM / 4;
  if (i >= NF4) return;
  f32x4 p = {0.f, 0.f, 0.f, 0.f};
#pragma unroll
  for (int c = 0; c < 4; c++) {
    u16x4 h = *reinterpret_cast<const u16x4*>(&partial[(size_t)c * ROWS * DIM + i * 4]);
#pragma unroll
    for (int r = 0; r < 4; r++) p[r] += __uint_as_float((unsigned)h[r] << 16);
  }
  f32x4 rr = ((const f32x4*)resid)[i];
  f32x4 bv = ((const f32x4*)bias)[i % (DIM / 4)];
  ((f32x4*)out)[i] = rr + p + bv;
}

// ---------------------------------------------------------------------------
// Flash attention v11 (proven 53.5us round 18): no-max softmax + deferred
// l-reduction; swapped QK^T, register P-transpose, wind prefetch, XCD grid.
// ---------------------------------------------------------------------------
__global__ __launch_bounds__(256) void wg_attn11(const __hip_bfloat16* __restrict__ Q,
                                                 const __hip_bfloat16* __restrict__ Kb,
                                                 const __hip_bfloat16* __restrict__ Vt,
                                                 const float* __restrict__ wb,
                                                 const float* __restrict__ beta,
                                                 __hip_bfloat16* __restrict__ O) {
  __shared__ __hip_bfloat16 Ks[2][4096];
  __shared__ __hip_bfloat16 Vs[2][4096];
  const int t = threadIdx.x;
  const int lane = t & 63;
  const int lhi = lane >> 4, llo = lane & 15;

  const int bid = blockIdx.x;
  const int wid = (bid & 7) * 96 + (bid >> 3);
  const int h = wid % NHEAD;
  const int g = wid / NHEAD;       // 0..63
  const int qt = g & 15;
  const int b = g >> 4;
  const float betah = beta[h] * 1.44269504089f;   // exp2 domain

  const int w = t >> 6;
  const size_t qrow0 = (size_t)b * SEQ + qt * 64 + w * 16;
  const __hip_bfloat16* Qp = Q + qrow0 * DIM + h * HD;
  bf16x8 a0 = *reinterpret_cast<const bf16x8*>(&Qp[(size_t)llo * DIM + lhi * 8]);
  bf16x8 a1 = *reinterpret_cast<const bf16x8*>(&Qp[(size_t)llo * DIM + 32 + lhi * 8]);

  const __hip_bfloat16* Kg = Kb + (size_t)b * SEQ * DIM + h * HD;
  const __hip_bfloat16* Vg = Vt + (size_t)(b * NHEAD + h) * HD * SEQ;
  const float* wrow = wb + (qrow0 + llo) * SEQ;

  const int slot0 = t, slot1 = t + 256;
  const int r0 = slot0 >> 3, c0 = (slot0 & 7) ^ (r0 & 7);
  const int r1 = slot1 >> 3, c1 = (slot1 & 7) ^ (r1 & 7);

  auto stage = [&](int buf, int kb) {
    GLDS16(Kg + (size_t)(kb + r0) * DIM + c0 * 8, &Ks[buf][slot0 * 8]);
    GLDS16(Kg + (size_t)(kb + r1) * DIM + c1 * 8, &Ks[buf][slot1 * 8]);
    GLDS16(Vg + (size_t)r0 * SEQ + kb + c0 * 8, &Vs[buf][slot0 * 8]);
    GLDS16(Vg + (size_t)r1 * SEQ + kb + c1 * 8, &Vs[buf][slot1 * 8]);
  };

  f32x4 zero = {0.f, 0.f, 0.f, 0.f};
  f32x4 oc[4];
#pragma unroll
  for (int c = 0; c < 4; c++) oc[c] = zero;
  float lacc = 0.f;

  f32x4 wv[4];
#pragma unroll
  for (int c2 = 0; c2 < 4; c2++)
    wv[c2] = *reinterpret_cast<const f32x4*>(&wrow[c2 * 16 + lhi * 4]);

  stage(0, 0);
  __syncthreads();
  int cur = 0;

  const int srcA = (lane & 15) | ((lane & 16) << 1);  // llo + 32*(lhi&1)
  const bool chi = (lane & 32) != 0;                  // lhi>>1

  for (int kt = 0; kt < SEQ / 64; kt++) {
    const int kb = kt * 64;
    f32x4 wvn[4];
    if (kt < SEQ / 64 - 1) {
      stage(cur ^ 1, kb + 64);
#pragma unroll
      for (int c2 = 0; c2 < 4; c2++)
        wvn[c2] = *reinterpret_cast<const f32x4*>(&wrow[kb + 64 + c2 * 16 + lhi * 4]);
    }

    // ---- swapped QK^T: lane holds S^T[kv=c2*16+lhi*4+r][q=llo] ----
    f32x4 sv[4];
    __builtin_amdgcn_s_setprio(1);
#pragma unroll
    for (int c2 = 0; c2 < 4; c2++) {
      const int row = c2 * 16 + llo;
      bf16x8 k0 = *reinterpret_cast<const bf16x8*>(
          &Ks[cur][((row << 3) + (lhi ^ (row & 7))) << 3]);
      bf16x8 k1 = *reinterpret_cast<const bf16x8*>(
          &Ks[cur][((row << 3) + ((4 + lhi) ^ (row & 7))) << 3]);
      f32x4 s_ = zero;
      s_ = MFMA16(k0, a0, s_);
      s_ = MFMA16(k1, a1, s_);
      sv[c2] = s_;
    }
    __builtin_amdgcn_s_setprio(0);

    // ---- bias + exp2 (no max; scale cancels in O/l) ----
#pragma unroll
    for (int c2 = 0; c2 < 4; c2++)
#pragma unroll
      for (int r = 0; r < 4; r++)
        sv[c2][r] = exp2f(sv[c2][r] + betah * wv[c2][r]);

    // ---- per-lane partial sum (cross-lane deferred to epilogue) ----
    f32x4 s4;
#pragma unroll
    for (int r = 0; r < 4; r++) s4[r] = (sv[0][r] + sv[1][r]) + (sv[2][r] + sv[3][r]);
    lacc += (s4[0] + s4[1]) + (s4[2] + s4[3]);

    // ---- P transpose in registers ----
    unsigned p01[4], p23[4];
#pragma unroll
    for (int c2 = 0; c2 < 4; c2++) {
      p01[c2] = pk2(sv[c2][0], sv[c2][1]);
      p23[c2] = pk2(sv[c2][2], sv[c2][3]);
    }
    unsigned a01_0A = (unsigned)__shfl((int)p01[0], srcA);
    unsigned a01_1A = (unsigned)__shfl((int)p01[1], srcA);
    unsigned a23_0A = (unsigned)__shfl((int)p23[0], srcA);
    unsigned a23_1A = (unsigned)__shfl((int)p23[1], srcA);
    unsigned a01_0B = (unsigned)__shfl((int)p01[0], srcA + 16);
    unsigned a01_1B = (unsigned)__shfl((int)p01[1], srcA + 16);
    unsigned a23_0B = (unsigned)__shfl((int)p23[0], srcA + 16);
    unsigned a23_1B = (unsigned)__shfl((int)p23[1], srcA + 16);
    unsigned b01_2A = (unsigned)__shfl((int)p01[2], srcA);
    unsigned b01_3A = (unsigned)__shfl((int)p01[3], srcA);
    unsigned b23_2A = (unsigned)__shfl((int)p23[2], srcA);
    unsigned b23_3A = (unsigned)__shfl((int)p23[3], srcA);
    unsigned b01_2B = (unsigned)__shfl((int)p01[2], srcA + 16);
    unsigned b01_3B = (unsigned)__shfl((int)p01[3], srcA + 16);
    unsigned b23_2B = (unsigned)__shfl((int)p23[2], srcA + 16);
    unsigned b23_3B = (unsigned)__shfl((int)p23[3], srcA + 16);
    u32x4 t0, t1;
    t0[0] = chi ? a01_1A : a01_0A;
    t0[1] = chi ? a23_1A : a23_0A;
    t0[2] = chi ? a01_1B : a01_0B;
    t0[3] = chi ? a23_1B : a23_0B;
    t1[0] = chi ? b01_3A : b01_2A;
    t1[1] = chi ? b23_3A : b23_2A;
    t1[2] = chi ? b01_3B : b01_2B;
    t1[3] = chi ? b23_3B : b23_2B;
    bf16x8 pf0 = __builtin_bit_cast(bf16x8, t0);
    bf16x8 pf1 = __builtin_bit_cast(bf16x8, t1);

    // ---- PV ----
    __builtin_amdgcn_s_setprio(1);
#pragma unroll
    for (int c = 0; c < 4; c++) {
      const int row = c * 16 + llo;
      bf16x8 v0 = *reinterpret_cast<const bf16x8*>(
          &Vs[cur][((row << 3) + (lhi ^ (row & 7))) << 3]);
      bf16x8 v1 = *reinterpret_cast<const bf16x8*>(
          &Vs[cur][((row << 3) + ((4 + lhi) ^ (row & 7))) << 3]);
      oc[c] = MFMA16(pf0, v0, oc[c]);
      oc[c] = MFMA16(pf1, v1, oc[c]);
    }
    __builtin_amdgcn_s_setprio(0);

    if (kt < SEQ / 64 - 1) {
#pragma unroll
      for (int c2 = 0; c2 < 4; c2++) wv[c2] = wvn[c2];
    }
    __syncthreads();
    cur ^= 1;
  }

  // epilogue: complete the l reduction (2 shuffles, once), then normalize
  float l_ = lacc;
  l_ += __shfl_xor(l_, 16);
  l_ += __shfl_xor(l_, 32);
  float iv[4];
  float invl = 1.0f / l_;
#pragma unroll
  for (int r = 0; r < 4; r++) iv[r] = __shfl(invl, lhi * 4 + r);
  __hip_bfloat16* Op = O + qrow0 * DIM + h * HD;
#pragma unroll
  for (int c = 0; c < 4; c++)
#pragma unroll
    for (int r = 0; r < 4; r++)
      Op[(size_t)(lhi * 4 + r) * DIM + c * 16 + llo] = __float2bfloat16(oc[c][r] * iv[r]);
}

// ---------------------------------------------------------------------------
// Launch
// ---------------------------------------------------------------------------
extern "C" void kernel_launch(void* const* d_in, const int* in_sizes, int n_in,
                              void* d_out, int out_size, void* d_ws, size_t ws_size,
                              hipStream_t stream) {
  const float* query = (const float*)d_in[0];
  const float* context = (const float*)d_in[1];
  const float* wind = (const float*)d_in[2];
  const float* ln_q_w = (const float*)d_in[3];
  const float* ln_q_b = (const float*)d_in[4];
  const float* ln_kv_w = (const float*)d_in[5];
  const float* ln_kv_b = (const float*)d_in[6];
  const float* Wq = (const float*)d_in[7];
  const float* bq = (const float*)d_in[8];
  const float* Wk = (const float*)d_in[9];
  const float* bk = (const float*)d_in[10];
  const float* Wv = (const float*)d_in[11];
  const float* bv = (const float*)d_in[12];
  const float* Wo = (const float*)d_in[13];
  const float* bo = (const float*)d_in[14];
  const float* beta = (const float*)d_in[15];
  const float* ln_f_w = (const float*)d_in[16];
  const float* ln_f_b = (const float*)d_in[17];
  const float* W1 = (const float*)d_in[18];
  const float* b1 = (const float*)d_in[19];
  const float* W2 = (const float*)d_in[20];
  const float* b2 = (const float*)d_in[21];
  float* out = (float*)d_out;

  char* ws = (char*)d_ws;
  size_t off = 0;
  auto take = [&](size_t bytes) -> char* {
    char* p = ws + off;
    off += (bytes + 255) & ~(size_t)255;
    return p;
  };
  const size_t actB = (size_t)ROWS * DIM * 2;
  __hip_bfloat16* qln = (__hip_bfloat16*)take(actB);
  __hip_bfloat16* kvln = (__hip_bfloat16*)take(actB);
  __hip_bfloat16* qb = (__hip_bfloat16*)take(actB);
  __hip_bfloat16* kbuf = (__hip_bfloat16*)take(actB);
  __hip_bfloat16* vt = (__hip_bfloat16*)take(actB);
  __hip_bfloat16* aout = (__hip_bfloat16*)take(actB);
  __hip_bfloat16* hbuf = (__hip_bfloat16*)take(actB);
  float* xbuf = (float*)take((size_t)ROWS * DIM * 4);
  __hip_bfloat16* hid = (__hip_bfloat16*)take((size_t)ROWS * HID * 2);
  __hip_bfloat16* WqT = (__hip_bfloat16*)take((size_t)DIM * DIM * 2);
  __hip_bfloat16* WkT = (__hip_bfloat16*)take((size_t)DIM * DIM * 2);
  __hip_bfloat16* WvT = (__hip_bfloat16*)take((size_t)DIM * DIM * 2);
  __hip_bfloat16* WoT = (__hip_bfloat16*)take((size_t)DIM * DIM * 2);
  __hip_bfloat16* W1T = (__hip_bfloat16*)take((size_t)DIM * HID * 2);
  __hip_bfloat16* W2T = (__hip_bfloat16*)take((size_t)HID * DIM * 2);
  __hip_bfloat16* kpart = (__hip_bfloat16*)take((size_t)4 * ROWS * DIM * 2);  // bf16 partials

  // prep: all weight transposes + dual LN in one launch
  wg_prep<<<6912 + 2 * ROWS, 256, 0, stream>>>(
      Wq, Wk, Wv, Wo, W1, W2, WqT, WkT, WvT, WoT, W1T, W2T,
      query, ln_q_w, ln_q_b, context, ln_kv_w, ln_kv_b, qln);

  const float scale = 0.125f * 1.44269504089f;  // hd^-0.5 * log2(e)
  // fused QKV: bias pointers bq/bk/bv passed via bias/resid/aux
  wg_gemm<6><<<32 * 18, 512, 0, stream>>>(qln, WqT, bq, qb, bk, (float*)bv,
                                          2304, DIM, DIM, scale, 32 * 18 / 8);

  wg_attn11<<<768, 256, 0, stream>>>(qb, kbuf, vt, wind, beta, aout);

  const int g768 = (ROWS / 128) * (DIM / 128);   // 192
  const int g3072 = (ROWS / 128) * (HID / 128);  // 768
  // O-proj fused: xbuf = query + aout*Wo + bo
  wg_gemm<3><<<g768, 512, 0, stream>>>(aout, WoT, bo, nullptr, query, xbuf,
                                       DIM, DIM, DIM, 0.f, g768 / 8);
  wg_ln1<<<ROWS, 256, 0, stream>>>(xbuf, ln_f_w, ln_f_b, hbuf);
  wg_gemm<4><<<g3072, 512, 0, stream>>>(hbuf, W1T, b1, hid, nullptr, nullptr,
                                        HID, DIM, DIM, 0.f, g3072 / 8);
  // MLP2 split-K=4, bf16 partials
  wg_gemm<7><<<dim3(g768, 4), 512, 0, stream>>>(hid, W2T, nullptr, nullptr, nullptr,
                                                (float*)kpart, DIM, HID / 4, HID, 0.f,
                                                g768 / 8);
  wg_redb<<<(ROWS * DIM / 4 + 255) / 256, 256, 0, stream>>>(kpart, xbuf, b2, out);
}